// Round 19
// baseline (56.882 us; speedup 1.0000x reference)
//
#include <hip/hip_runtime.h>
#include <stdint.h>

#define BATCH 16
#define NPTS 4096
#define DIM 384
#define NTOK (2*NPTS)
#define F4PT (DIM/4)   // 96 float4 groups per token

typedef unsigned long long u64;
typedef float nfloat4 __attribute__((ext_vector_type(4)));   // native vec for nt-store

// Morton spread: place bit b of an 8-bit value at position 3b.
__device__ __forceinline__ uint32_t spread3(uint32_t x) {
    x = (x | (x << 8)) & 0x00F00Fu;
    x = (x | (x << 4)) & 0x0C30C3u;
    x = (x | (x << 2)) & 0x249249u;
    return x;
}

// Exact port of the reference Skilling transform (bits=8, ndim=3).
__device__ __forceinline__ uint32_t hilbert3(uint32_t x0, uint32_t x1, uint32_t x2) {
    #pragma unroll
    for (uint32_t q = 128; q > 1; q >>= 1) {
        uint32_t pm = q - 1;
        if (x0 & q) x0 ^= pm;
        uint32_t t = (x0 ^ x1) & pm;
        if (x1 & q) { x0 ^= pm; } else { x0 ^= t; x1 ^= t; }
        t = (x0 ^ x2) & pm;
        if (x2 & q) { x0 ^= pm; } else { x0 ^= t; x2 ^= t; }
    }
    x1 ^= x0;
    x2 ^= x1;
    uint32_t t = 0;
    #pragma unroll
    for (uint32_t q = 128; q > 1; q >>= 1) { if (x2 & q) t ^= (q - 1); }
    x0 ^= t; x1 ^= t; x2 ^= t;
    return (spread3(x0) << 2) | (spread3(x1) << 1) | spread3(x2);
}

// K1: block = (b, v, octant). 512 threads, 1 element each. Batch minmax
// (48 KB, L2-hot, redundant per block - cheap), code own point, 3-pass 8-bit
// STABLE radix sort of the 512-element octant by code only (stability makes
// idx a pure payload), write sorted run as split u32 code / u16 idx arrays.
__global__ __launch_bounds__(512) void order_radix_o(const float* __restrict__ x,
                                                     uint32_t* __restrict__ segc_all,
                                                     unsigned short* __restrict__ segi_all) {
    const int bi = blockIdx.x;
    const int b = bi >> 4;
    const int v = (bi >> 3) & 1;
    const int oct = bi & 7;
    const int t = threadIdx.x;
    const int lane = t & 63;
    const int w = t >> 6;          // 8 waves

    __shared__ uint32_t scode[512];          // 2 KB
    __shared__ unsigned short slocal[512];   // 1 KB
    __shared__ uint32_t hist[3 * 2048];      // per-pass hist[p][d*8+w], 24 KB
    __shared__ uint32_t baseArr[256];        // 1 KB
    __shared__ uint32_t waveTot[4];
    __shared__ float red[8 * 6];

    const float* xb = x + (size_t)b * NPTS * 3;
    const float4* xb4 = (const float4*)xb;

    // --- vectorized batch min/max: 8 points/thread ---
    float mnx = 1e30f, mny = 1e30f, mnz = 1e30f;
    float mxx = -1e30f, mxy = -1e30f, mxz = -1e30f;
    #pragma unroll
    for (int h = 0; h < 2; ++h) {
        float4 q0 = xb4[h * 1536 + 3 * t + 0];
        float4 q1 = xb4[h * 1536 + 3 * t + 1];
        float4 q2 = xb4[h * 1536 + 3 * t + 2];
        float px[4] = {q0.x, q0.w, q1.z, q2.y};
        float py[4] = {q0.y, q1.x, q1.w, q2.z};
        float pz[4] = {q0.z, q1.y, q2.x, q2.w};
        #pragma unroll
        for (int r = 0; r < 4; ++r) {
            mnx = fminf(mnx, px[r]); mxx = fmaxf(mxx, px[r]);
            mny = fminf(mny, py[r]); mxy = fmaxf(mxy, py[r]);
            mnz = fminf(mnz, pz[r]); mxz = fmaxf(mxz, pz[r]);
        }
    }
    #pragma unroll
    for (int off = 32; off > 0; off >>= 1) {
        mnx = fminf(mnx, __shfl_xor(mnx, off));
        mny = fminf(mny, __shfl_xor(mny, off));
        mnz = fminf(mnz, __shfl_xor(mnz, off));
        mxx = fmaxf(mxx, __shfl_xor(mxx, off));
        mxy = fmaxf(mxy, __shfl_xor(mxy, off));
        mxz = fmaxf(mxz, __shfl_xor(mxz, off));
    }
    if (lane == 0) {
        red[w*6+0] = mnx; red[w*6+1] = mny; red[w*6+2] = mnz;
        red[w*6+3] = mxx; red[w*6+4] = mxy; red[w*6+5] = mxz;
    }
    // Zero all per-pass hist regions while the reduction settles.
    #pragma unroll
    for (int c = 0; c < 12; ++c) hist[t + c * 512] = 0u;
    __syncthreads();
    if (t == 0) {
        for (int ww = 1; ww < 8; ++ww) {
            mnx = fminf(mnx, red[ww*6+0]); mny = fminf(mny, red[ww*6+1]);
            mnz = fminf(mnz, red[ww*6+2]); mxx = fmaxf(mxx, red[ww*6+3]);
            mxy = fmaxf(mxy, red[ww*6+4]); mxz = fmaxf(mxz, red[ww*6+5]);
        }
        red[0] = mnx; red[1] = mny; red[2] = mnz;
        red[3] = fmaxf(mxx - mnx, 1e-6f);
        red[4] = fmaxf(mxy - mny, 1e-6f);
        red[5] = fmaxf(mxz - mnz, 1e-6f);
    }
    __syncthreads();
    mnx = red[0]; mny = red[1]; mnz = red[2];
    const float spx = red[3], spy = red[4], spz = red[5];

    // Code own point n0 = oct*512 + t.
    uint32_t code;
    unsigned short myidx;
    {
        const int n0 = (oct << 9) + t;
        float cx = xb[3*n0+0], cy = xb[3*n0+1], cz = xb[3*n0+2];
        float gx = fminf(fmaxf(((cx - mnx) / spx) * 255.0f, 0.0f), 255.0f);
        float gy = fminf(fmaxf(((cy - mny) / spy) * 255.0f, 0.0f), 255.0f);
        float gz = fminf(fmaxf(((cz - mnz) / spz) * 255.0f, 0.0f), 255.0f);
        uint32_t ix = (uint32_t)(int)gx;
        uint32_t iy = (uint32_t)(int)gy;
        uint32_t iz = (uint32_t)(int)gz;
        uint32_t a0 = v ? iz : ix;
        uint32_t a2 = v ? ix : iz;
        code = hilbert3(a0, iy, a2);
        myidx = (unsigned short)n0;
    }

    const u64 below_mask = (1ull << lane) - 1ull;
    uint32_t* segc = segc_all + (((b << 1) | v) << 12);
    unsigned short* segi = segi_all + (((b << 1) | v) << 12);

    // 3 stable radix passes, 8-bit digits over code bits [0, 24).
    #pragma unroll
    for (int p = 0; p < 3; ++p) {
        const int sh = 8 * p;
        uint32_t* histp = hist + p * 2048;

        unsigned d = (code >> sh) & 255u;
        u64 m = ~0ull;
        #pragma unroll
        for (int bit = 0; bit < 8; ++bit) {
            u64 bal = __ballot((int)((d >> bit) & 1u));
            m &= ((d >> bit) & 1u) ? bal : ~bal;
        }
        unsigned rk = (unsigned)__popcll(m & below_mask);
        if (rk == 0u)
            histp[d * 8 + w] = (unsigned)__popcll(m);
        __syncthreads();   // B1

        // 256 threads: serial-scan own bin's 8 slots; 4-wave shfl scan of
        // bin totals; waveTot combine after barrier.
        unsigned exclw = 0;
        if (t < 256) {
            uint32_t* hb = histp + t * 8;
            unsigned running = 0;
            #pragma unroll
            for (int s = 0; s < 8; ++s) {
                unsigned hv = hb[s];
                hb[s] = running;
                running += hv;
            }
            unsigned incl = running;
            #pragma unroll
            for (int off = 1; off < 64; off <<= 1) {
                unsigned nv = __shfl_up(incl, off);
                if (lane >= off) incl += nv;
            }
            if (lane == 63) waveTot[w] = incl;
            exclw = incl - running;
        }
        __syncthreads();   // B1.5

        if (t < 256) {
            unsigned base = exclw;
            #pragma unroll
            for (int ww = 0; ww < 4; ++ww)
                if (ww < w) base += waveTot[ww];
            baseArr[t] = base;
        }
        __syncthreads();   // B2

        unsigned pos = baseArr[d] + histp[d * 8 + w] + rk;

        if (p < 2) {
            scode[pos] = code;
            slocal[pos] = myidx;
            __syncthreads();   // B3
            code = scode[t];
            myidx = slocal[t];
        } else {
            segc[(oct << 9) + pos] = code;
            segi[(oct << 9) + pos] = myidx;
        }
    }
}

// K2: block = (b, v, octant). Early-loads own code/idx/coords (hidden under
// staging), stages all 8 runs' CODES (16 KB, uint4 loads), ranks each own
// element via 7 interleaved binary searches with run-order tie-break
// (count in run j = #{c' < kc + (j < oct)} -- exact argsort rank since run
// idx-ranges are disjoint and ordered), then emits the 512 output rows with
// non-temporal stores (output is write-once, never re-read).
__global__ __launch_bounds__(512) void merge_emit_kernel(const float* __restrict__ x,
                                                         const float* __restrict__ W,
                                                         const float* __restrict__ bias,
                                                         const float* __restrict__ gamma,
                                                         const float* __restrict__ beta,
                                                         const uint32_t* __restrict__ segc_all,
                                                         const unsigned short* __restrict__ segi_all,
                                                         nfloat4* __restrict__ out4) {
    const int bi = blockIdx.x;
    const int b = bi >> 4;
    const int v = (bi >> 3) & 1;
    const int oct = bi & 7;
    const int t = threadIdx.x;

    __shared__ uint32_t runs[8 * 512];                  // 16 KB
    __shared__ __align__(16) float sw0[DIM], sw1[DIM], sw2[DIM], sc[DIM];  // 6 KB
    __shared__ float cxs[512], cys[512], czs[512];      // 6 KB
    __shared__ int rnk[512];                            // 2 KB

    const uint32_t* segc = segc_all + (((b << 1) | v) << 12);
    const unsigned short* segi = segi_all + (((b << 1) | v) << 12);

    // Early independent loads: own code, idx, coords (chained; lands under
    // the staging + barrier below).
    uint32_t kc = segc[(oct << 9) + t];
    int idx = (int)segi[(oct << 9) + t];
    const float* p = x + (size_t)b * NPTS * 3 + idx * 3;
    float pcx = p[0], pcy = p[1], pcz = p[2];

    // Coeffs (fused gamma/beta), one v per block.
    if (t < DIM) {
        float g = gamma[v * DIM + t];
        sw0[t] = g * W[t*3+0];
        sw1[t] = g * W[t*3+1];
        sw2[t] = g * W[t*3+2];
        sc[t]  = g * bias[t] + beta[v * DIM + t];
    }

    // Stage all 8 runs' codes as uint4 (2 x 16 B per thread).
    {
        const uint4* s4 = (const uint4*)segc;
        uint4* r4 = (uint4*)runs;
        r4[t] = s4[t];
        r4[t + 512] = s4[t + 512];
    }
    __syncthreads();

    // Rank = own position + counts in the other 7 runs.
    int rank = t;
    {
        int base7[7];
        uint32_t thr7[7];
        int c[7];
        #pragma unroll
        for (int j = 0; j < 7; ++j) {
            int oq = j + (j >= oct ? 1 : 0);
            base7[j] = oq << 9;
            thr7[j] = kc + (oq < oct ? 1u : 0u);
            c[j] = 0;
        }
        #pragma unroll
        for (int step = 512; step >= 1; step >>= 1) {
            #pragma unroll
            for (int j = 0; j < 7; ++j) {
                if (c[j] + step <= 512 && runs[base7[j] + c[j] + step - 1] < thr7[j])
                    c[j] += step;
            }
        }
        #pragma unroll
        for (int j = 0; j < 7; ++j) rank += c[j];
    }

    cxs[t] = pcx; cys[t] = pcy; czs[t] = pcz;
    rnk[t] = rank;
    __syncthreads();

    // Emit 512 rows x 96 float4 groups; lane-contiguous within rows;
    // non-temporal (streaming) stores.
    const int tokbase = (b << 13) + (v << 12);
    for (int i = t; i < 512 * F4PT; i += 512) {
        int r = i / F4PT;
        int g = i - r * F4PT;
        float pxr = cxs[r], pyr = cys[r], pzr = czs[r];
        int d0 = g << 2;
        float4 w0 = *(const float4*)&sw0[d0];
        float4 w1 = *(const float4*)&sw1[d0];
        float4 w2 = *(const float4*)&sw2[d0];
        float4 cc = *(const float4*)&sc[d0];
        nfloat4 o;
        o.x = pxr*w0.x + pyr*w1.x + pzr*w2.x + cc.x;
        o.y = pxr*w0.y + pyr*w1.y + pzr*w2.y + cc.y;
        o.z = pxr*w0.z + pyr*w1.z + pzr*w2.z + cc.z;
        o.w = pxr*w0.w + pyr*w1.w + pzr*w2.w + cc.w;
        __builtin_nontemporal_store(o, &out4[(size_t)(tokbase + rnk[r]) * F4PT + g]);
    }
}

extern "C" void kernel_launch(void* const* d_in, const int* in_sizes, int n_in,
                              void* d_out, int out_size, void* d_ws, size_t ws_size,
                              hipStream_t stream) {
    const float* x     = (const float*)d_in[0];
    const float* W     = (const float*)d_in[1];
    const float* bias  = (const float*)d_in[2];
    const float* gamma = (const float*)d_in[3];
    const float* beta  = (const float*)d_in[4];

    uint32_t* segc_all = (uint32_t*)d_ws;                       // 32*4096*4 = 512 KB
    unsigned short* segi_all = (unsigned short*)(segc_all + 32 * 4096);  // 256 KB

    hipLaunchKernelGGL(order_radix_o,     dim3(BATCH * 16), dim3(512), 0, stream,
                       x, segc_all, segi_all);
    hipLaunchKernelGGL(merge_emit_kernel, dim3(BATCH * 16), dim3(512), 0, stream,
                       x, W, bias, gamma, beta, segc_all, segi_all, (nfloat4*)d_out);
}

// Round 20
// 49.520 us; speedup vs baseline: 1.1487x; 1.1487x over previous
//
#include <hip/hip_runtime.h>
#include <stdint.h>

#define BATCH 16
#define NPTS 4096
#define DIM 384
#define NTOK (2*NPTS)
#define F4PT (DIM/4)   // 96 float4 groups per token

typedef unsigned long long u64;

// Morton spread: place bit b of an 8-bit value at position 3b.
__device__ __forceinline__ uint32_t spread3(uint32_t x) {
    x = (x | (x << 8)) & 0x00F00Fu;
    x = (x | (x << 4)) & 0x0C30C3u;
    x = (x | (x << 2)) & 0x249249u;
    return x;
}

// Exact port of the reference Skilling transform (bits=8, ndim=3).
__device__ __forceinline__ uint32_t hilbert3(uint32_t x0, uint32_t x1, uint32_t x2) {
    #pragma unroll
    for (uint32_t q = 128; q > 1; q >>= 1) {
        uint32_t pm = q - 1;
        if (x0 & q) x0 ^= pm;
        uint32_t t = (x0 ^ x1) & pm;
        if (x1 & q) { x0 ^= pm; } else { x0 ^= t; x1 ^= t; }
        t = (x0 ^ x2) & pm;
        if (x2 & q) { x0 ^= pm; } else { x0 ^= t; x2 ^= t; }
    }
    x1 ^= x0;
    x2 ^= x1;
    uint32_t t = 0;
    #pragma unroll
    for (uint32_t q = 128; q > 1; q >>= 1) { if (x2 & q) t ^= (q - 1); }
    x0 ^= t; x1 ^= t; x2 ^= t;
    return (spread3(x0) << 2) | (spread3(x1) << 1) | spread3(x2);
}

// K1: block = (b, v, octant). 512 threads, 1 element each. Batch minmax
// (48 KB, L2-hot, redundant per block - cheap), code own point, 3-pass 8-bit
// STABLE radix sort of the 512-element octant by code only (stability makes
// idx a pure payload), write sorted run as split u32 code / u16 idx arrays.
__global__ __launch_bounds__(512) void order_radix_o(const float* __restrict__ x,
                                                     uint32_t* __restrict__ segc_all,
                                                     unsigned short* __restrict__ segi_all) {
    const int bi = blockIdx.x;
    const int b = bi >> 4;
    const int v = (bi >> 3) & 1;
    const int oct = bi & 7;
    const int t = threadIdx.x;
    const int lane = t & 63;
    const int w = t >> 6;          // 8 waves

    __shared__ uint32_t scode[512];          // 2 KB
    __shared__ unsigned short slocal[512];   // 1 KB
    __shared__ uint32_t hist[3 * 2048];      // per-pass hist[p][d*8+w], 24 KB
    __shared__ uint32_t baseArr[256];        // 1 KB
    __shared__ uint32_t waveTot[4];
    __shared__ float red[8 * 6];

    const float* xb = x + (size_t)b * NPTS * 3;
    const float4* xb4 = (const float4*)xb;

    // --- vectorized batch min/max: 8 points/thread ---
    float mnx = 1e30f, mny = 1e30f, mnz = 1e30f;
    float mxx = -1e30f, mxy = -1e30f, mxz = -1e30f;
    #pragma unroll
    for (int h = 0; h < 2; ++h) {
        float4 q0 = xb4[h * 1536 + 3 * t + 0];
        float4 q1 = xb4[h * 1536 + 3 * t + 1];
        float4 q2 = xb4[h * 1536 + 3 * t + 2];
        float px[4] = {q0.x, q0.w, q1.z, q2.y};
        float py[4] = {q0.y, q1.x, q1.w, q2.z};
        float pz[4] = {q0.z, q1.y, q2.x, q2.w};
        #pragma unroll
        for (int r = 0; r < 4; ++r) {
            mnx = fminf(mnx, px[r]); mxx = fmaxf(mxx, px[r]);
            mny = fminf(mny, py[r]); mxy = fmaxf(mxy, py[r]);
            mnz = fminf(mnz, pz[r]); mxz = fmaxf(mxz, pz[r]);
        }
    }
    #pragma unroll
    for (int off = 32; off > 0; off >>= 1) {
        mnx = fminf(mnx, __shfl_xor(mnx, off));
        mny = fminf(mny, __shfl_xor(mny, off));
        mnz = fminf(mnz, __shfl_xor(mnz, off));
        mxx = fmaxf(mxx, __shfl_xor(mxx, off));
        mxy = fmaxf(mxy, __shfl_xor(mxy, off));
        mxz = fmaxf(mxz, __shfl_xor(mxz, off));
    }
    if (lane == 0) {
        red[w*6+0] = mnx; red[w*6+1] = mny; red[w*6+2] = mnz;
        red[w*6+3] = mxx; red[w*6+4] = mxy; red[w*6+5] = mxz;
    }
    // Zero all per-pass hist regions while the reduction settles.
    #pragma unroll
    for (int c = 0; c < 12; ++c) hist[t + c * 512] = 0u;
    __syncthreads();
    if (t == 0) {
        for (int ww = 1; ww < 8; ++ww) {
            mnx = fminf(mnx, red[ww*6+0]); mny = fminf(mny, red[ww*6+1]);
            mnz = fminf(mnz, red[ww*6+2]); mxx = fmaxf(mxx, red[ww*6+3]);
            mxy = fmaxf(mxy, red[ww*6+4]); mxz = fmaxf(mxz, red[ww*6+5]);
        }
        red[0] = mnx; red[1] = mny; red[2] = mnz;
        red[3] = fmaxf(mxx - mnx, 1e-6f);
        red[4] = fmaxf(mxy - mny, 1e-6f);
        red[5] = fmaxf(mxz - mnz, 1e-6f);
    }
    __syncthreads();
    mnx = red[0]; mny = red[1]; mnz = red[2];
    const float spx = red[3], spy = red[4], spz = red[5];

    // Code own point n0 = oct*512 + t.
    uint32_t code;
    unsigned short myidx;
    {
        const int n0 = (oct << 9) + t;
        float cx = xb[3*n0+0], cy = xb[3*n0+1], cz = xb[3*n0+2];
        float gx = fminf(fmaxf(((cx - mnx) / spx) * 255.0f, 0.0f), 255.0f);
        float gy = fminf(fmaxf(((cy - mny) / spy) * 255.0f, 0.0f), 255.0f);
        float gz = fminf(fmaxf(((cz - mnz) / spz) * 255.0f, 0.0f), 255.0f);
        uint32_t ix = (uint32_t)(int)gx;
        uint32_t iy = (uint32_t)(int)gy;
        uint32_t iz = (uint32_t)(int)gz;
        uint32_t a0 = v ? iz : ix;
        uint32_t a2 = v ? ix : iz;
        code = hilbert3(a0, iy, a2);
        myidx = (unsigned short)n0;
    }

    const u64 below_mask = (1ull << lane) - 1ull;
    uint32_t* segc = segc_all + (((b << 1) | v) << 12);
    unsigned short* segi = segi_all + (((b << 1) | v) << 12);

    // 3 stable radix passes, 8-bit digits over code bits [0, 24).
    #pragma unroll
    for (int p = 0; p < 3; ++p) {
        const int sh = 8 * p;
        uint32_t* histp = hist + p * 2048;

        unsigned d = (code >> sh) & 255u;
        u64 m = ~0ull;
        #pragma unroll
        for (int bit = 0; bit < 8; ++bit) {
            u64 bal = __ballot((int)((d >> bit) & 1u));
            m &= ((d >> bit) & 1u) ? bal : ~bal;
        }
        unsigned rk = (unsigned)__popcll(m & below_mask);
        if (rk == 0u)
            histp[d * 8 + w] = (unsigned)__popcll(m);
        __syncthreads();   // B1

        // 256 threads: serial-scan own bin's 8 slots; 4-wave shfl scan of
        // bin totals; waveTot combine after barrier.
        unsigned exclw = 0;
        if (t < 256) {
            uint32_t* hb = histp + t * 8;
            unsigned running = 0;
            #pragma unroll
            for (int s = 0; s < 8; ++s) {
                unsigned hv = hb[s];
                hb[s] = running;
                running += hv;
            }
            unsigned incl = running;
            #pragma unroll
            for (int off = 1; off < 64; off <<= 1) {
                unsigned nv = __shfl_up(incl, off);
                if (lane >= off) incl += nv;
            }
            if (lane == 63) waveTot[w] = incl;
            exclw = incl - running;
        }
        __syncthreads();   // B1.5

        if (t < 256) {
            unsigned base = exclw;
            #pragma unroll
            for (int ww = 0; ww < 4; ++ww)
                if (ww < w) base += waveTot[ww];
            baseArr[t] = base;
        }
        __syncthreads();   // B2

        unsigned pos = baseArr[d] + histp[d * 8 + w] + rk;

        if (p < 2) {
            scode[pos] = code;
            slocal[pos] = myidx;
            __syncthreads();   // B3
            code = scode[t];
            myidx = slocal[t];
        } else {
            segc[(oct << 9) + pos] = code;
            segi[(oct << 9) + pos] = myidx;
        }
    }
}

// K2: block = (b, v, octant). Early-loads own code/idx/coords (hidden under
// staging), stages all 8 runs' CODES (16 KB, uint4 loads), ranks each own
// element via 7 interleaved binary searches with run-order tie-break
// (count in run j = #{c' < kc + (j < oct)} -- exact argsort rank since run
// idx-ranges are disjoint and ordered), then emits the 512 output rows.
__global__ __launch_bounds__(512) void merge_emit_kernel(const float* __restrict__ x,
                                                         const float* __restrict__ W,
                                                         const float* __restrict__ bias,
                                                         const float* __restrict__ gamma,
                                                         const float* __restrict__ beta,
                                                         const uint32_t* __restrict__ segc_all,
                                                         const unsigned short* __restrict__ segi_all,
                                                         float4* __restrict__ out4) {
    const int bi = blockIdx.x;
    const int b = bi >> 4;
    const int v = (bi >> 3) & 1;
    const int oct = bi & 7;
    const int t = threadIdx.x;

    __shared__ uint32_t runs[8 * 512];                  // 16 KB
    __shared__ __align__(16) float sw0[DIM], sw1[DIM], sw2[DIM], sc[DIM];  // 6 KB
    __shared__ float cxs[512], cys[512], czs[512];      // 6 KB
    __shared__ int rnk[512];                            // 2 KB

    const uint32_t* segc = segc_all + (((b << 1) | v) << 12);
    const unsigned short* segi = segi_all + (((b << 1) | v) << 12);

    // Early independent loads: own code, idx, coords (chained; lands under
    // the staging + barrier below).
    uint32_t kc = segc[(oct << 9) + t];
    int idx = (int)segi[(oct << 9) + t];
    const float* p = x + (size_t)b * NPTS * 3 + idx * 3;
    float pcx = p[0], pcy = p[1], pcz = p[2];

    // Coeffs (fused gamma/beta), one v per block.
    if (t < DIM) {
        float g = gamma[v * DIM + t];
        sw0[t] = g * W[t*3+0];
        sw1[t] = g * W[t*3+1];
        sw2[t] = g * W[t*3+2];
        sc[t]  = g * bias[t] + beta[v * DIM + t];
    }

    // Stage all 8 runs' codes as uint4 (2 x 16 B per thread).
    {
        const uint4* s4 = (const uint4*)segc;
        uint4* r4 = (uint4*)runs;
        r4[t] = s4[t];
        r4[t + 512] = s4[t + 512];
    }
    __syncthreads();

    // Rank = own position + counts in the other 7 runs.
    int rank = t;
    {
        int base7[7];
        uint32_t thr7[7];
        int c[7];
        #pragma unroll
        for (int j = 0; j < 7; ++j) {
            int oq = j + (j >= oct ? 1 : 0);
            base7[j] = oq << 9;
            thr7[j] = kc + (oq < oct ? 1u : 0u);
            c[j] = 0;
        }
        #pragma unroll
        for (int step = 512; step >= 1; step >>= 1) {
            #pragma unroll
            for (int j = 0; j < 7; ++j) {
                if (c[j] + step <= 512 && runs[base7[j] + c[j] + step - 1] < thr7[j])
                    c[j] += step;
            }
        }
        #pragma unroll
        for (int j = 0; j < 7; ++j) rank += c[j];
    }

    cxs[t] = pcx; cys[t] = pcy; czs[t] = pcz;
    rnk[t] = rank;
    __syncthreads();

    // Emit 512 rows x 96 float4 groups; lane-contiguous within rows.
    const int tokbase = (b << 13) + (v << 12);
    for (int i = t; i < 512 * F4PT; i += 512) {
        int r = i / F4PT;
        int g = i - r * F4PT;
        float pxr = cxs[r], pyr = cys[r], pzr = czs[r];
        int d0 = g << 2;
        float4 w0 = *(const float4*)&sw0[d0];
        float4 w1 = *(const float4*)&sw1[d0];
        float4 w2 = *(const float4*)&sw2[d0];
        float4 cc = *(const float4*)&sc[d0];
        float4 o;
        o.x = pxr*w0.x + pyr*w1.x + pzr*w2.x + cc.x;
        o.y = pxr*w0.y + pyr*w1.y + pzr*w2.y + cc.y;
        o.z = pxr*w0.z + pyr*w1.z + pzr*w2.z + cc.z;
        o.w = pxr*w0.w + pyr*w1.w + pzr*w2.w + cc.w;
        out4[(size_t)(tokbase + rnk[r]) * F4PT + g] = o;
    }
}

extern "C" void kernel_launch(void* const* d_in, const int* in_sizes, int n_in,
                              void* d_out, int out_size, void* d_ws, size_t ws_size,
                              hipStream_t stream) {
    const float* x     = (const float*)d_in[0];
    const float* W     = (const float*)d_in[1];
    const float* bias  = (const float*)d_in[2];
    const float* gamma = (const float*)d_in[3];
    const float* beta  = (const float*)d_in[4];

    uint32_t* segc_all = (uint32_t*)d_ws;                       // 32*4096*4 = 512 KB
    unsigned short* segi_all = (unsigned short*)(segc_all + 32 * 4096);  // 256 KB

    hipLaunchKernelGGL(order_radix_o,     dim3(BATCH * 16), dim3(512), 0, stream,
                       x, segc_all, segi_all);
    hipLaunchKernelGGL(merge_emit_kernel, dim3(BATCH * 16), dim3(512), 0, stream,
                       x, W, bias, gamma, beta, segc_all, segi_all, (float4*)d_out);
}